// Round 12
// baseline (259.903 us; speedup 1.0000x reference)
//
#include <hip/hip_runtime.h>
#include <math.h>

#define T_SEQ 2048
#define NB 4
#define NH 16
#define DH 64
#define DM 1024

typedef __attribute__((ext_vector_type(8))) __bf16 bf16x8;
typedef __attribute__((ext_vector_type(4))) float f32x4;

typedef const __attribute__((address_space(1))) void* gas_t;
typedef __attribute__((address_space(3))) void* las_t;

#if __has_builtin(__builtin_amdgcn_exp2f)
#define EXP2(x) __builtin_amdgcn_exp2f(x)
#else
#define EXP2(x) __expf((x) * 0.69314718056f)
#endif

#define SCHED0 __builtin_amdgcn_sched_barrier(0)
#define GLD(src, dst) __builtin_amdgcn_global_load_lds((gas_t)(src), (las_t)(dst), 16, 0, 0)
#define WAIT_VM(N) asm volatile("s_waitcnt vmcnt(" #N ")" ::: "memory")
#define WAIT_LGKM0 asm volatile("s_waitcnt lgkmcnt(0)" ::: "memory")
#define MEMFENCE   asm volatile("" ::: "memory")

// ---- dtype detection (kept for fallback tiers)
__device__ inline bool detect_f32(const unsigned short* probe, int lane) {
    unsigned short u = probe[lane];
    int e = (u >> 7) & 0xFF;
    bool outlier = (e >= 140) || (e <= 90 && (u & 0x7fff) != 0);
    unsigned long long m = __ballot(outlier);
    return __popcll(m) >= 4;
}

__device__ inline bf16x8 load8_flex(const void* base, long elem, bool f32) {
    if (!f32) {
        return *(const bf16x8*)((const __bf16*)base + elem);
    } else {
        const float* f = (const float*)base + elem;
        float4 a = *(const float4*)f;
        float4 b = *(const float4*)(f + 4);
        bf16x8 r;
        r[0] = (__bf16)a.x; r[1] = (__bf16)a.y; r[2] = (__bf16)a.z; r[3] = (__bf16)a.w;
        r[4] = (__bf16)b.x; r[5] = (__bf16)b.y; r[6] = (__bf16)b.z; r[7] = (__bf16)b.w;
        return r;
    }
}

// ---------------- fp32 -> bf16 elementwise convert -------------------------
__global__ __launch_bounds__(256)
void cvt_x(const float* __restrict__ in, __bf16* __restrict__ out, long n8) {
    long i = (long)blockIdx.x * blockDim.x + threadIdx.x;
    if (i >= n8) return;
    const float* f = in + i * 8;
    float4 a = *(const float4*)f;
    float4 b = *(const float4*)(f + 4);
    bf16x8 r;
    r[0] = (__bf16)a.x; r[1] = (__bf16)a.y; r[2] = (__bf16)a.z; r[3] = (__bf16)a.w;
    r[4] = (__bf16)b.x; r[5] = (__bf16)b.y; r[6] = (__bf16)b.z; r[7] = (__bf16)b.w;
    *(bf16x8*)(out + i * 8) = r;
}

// ---------------- fp32 [R][C] -> bf16 [C][R] transpose+convert -------------
__global__ __launch_bounds__(256)
void tpose_cvt(const float* __restrict__ in, __bf16* __restrict__ out, int R, int C) {
    __shared__ __bf16 tile[32][33];
    const int bx = blockIdx.x * 32;
    const int by = blockIdx.y * 32;
    const int tx = threadIdx.x & 31;
    const int ty = threadIdx.x >> 5;
#pragma unroll
    for (int it = 0; it < 4; ++it) {
        int r = ty + it * 8;
        tile[r][tx] = (__bf16)in[(long)(by + r) * C + bx + tx];
    }
    __syncthreads();
#pragma unroll
    for (int it = 0; it < 4; ++it) {
        int r = ty + it * 8;
        out[(long)(bx + r) * R + by + tx] = tile[tx][r];
    }
}

// ---------------- ring-3 pipelined 128x128 GEMM (gemm1) --------------------
// R9 structure, unchanged.
__global__ __launch_bounds__(256, 3)
void gemm_p3(const __bf16* __restrict__ A, long lda,
             const __bf16* __restrict__ Bt, long ldb,
             void* __restrict__ C, long ldc, int c_f32, int K) {
    constexpr int AUNIT = 128 * 32;          // 4096 elems = 8 KiB
    constexpr int UNIT  = 2 * AUNIT;         // A + B = 16 KiB
    __shared__ __align__(16) __bf16 lds[3 * UNIT];   // 48 KiB

    const int tid  = threadIdx.x;
    const int lane = tid & 63;
    const int wave = tid >> 6;               // 0..3
    const int l15  = lane & 15;
    const int quad = lane >> 4;

    const int wg   = blockIdx.x;
    const int xcd  = wg & 7;
    const int idx  = wg >> 3;
    const int bm   = (xcd * 8 + (idx & 7)) * 128;
    const int bn   = (idx >> 3) * 128;

    const int wm = (wave & 1) * 64;
    const int wn = (wave >> 1) * 64;

    f32x4 zero = {0.f, 0.f, 0.f, 0.f};
    f32x4 acc[4][4];
#pragma unroll
    for (int i = 0; i < 4; ++i)
#pragma unroll
        for (int j = 0; j < 4; ++j) acc[i][j] = zero;

    const int srow  = lane >> 2;             // 0..15
    const int swcol = ((lane & 3) ^ ((lane >> 3) & 3)) * 8;
    const __bf16* aS = A  + (long)(bm + wave * 32 + srow) * lda + swcol;
    const __bf16* bS = Bt + (long)(bn + wave * 32 + srow) * ldb + swcol;

    const int rcol = (quad ^ ((l15 >> 1) & 3)) * 8;

    const int NHALF = K >> 5;

    // ---- prologue: stage units 0,1 ----
#pragma unroll
    for (int u = 0; u < 2; ++u) {
        __bf16* wU = lds + u * UNIT;
        const long kc = (long)u * 32;
        GLD(aS + kc,            wU + wave * 1024);
        GLD(aS + 16 * lda + kc, wU + wave * 1024 + 512);
        GLD(bS + kc,            wU + AUNIT + wave * 1024);
        GLD(bS + 16 * ldb + kc, wU + AUNIT + wave * 1024 + 512);
    }
    SCHED0;
    WAIT_VM(4);
    SCHED0;
    __builtin_amdgcn_s_barrier();
    SCHED0;

    int cu = 0;
    int su = 2;
    for (int h = 0; h < NHALF; ++h) {
        const __bf16* uA = lds + cu * UNIT;
        const __bf16* uB = uA + AUNIT;

        bf16x8 af[4], bf[4];
#pragma unroll
        for (int i = 0; i < 4; ++i)
            af[i] = *(const bf16x8*)(uA + (wm + i * 16 + l15) * 32 + rcol);
#pragma unroll
        for (int j = 0; j < 4; ++j)
            bf[j] = *(const bf16x8*)(uB + (wn + j * 16 + l15) * 32 + rcol);

        if (h + 2 < NHALF) {
            __bf16* wU = lds + su * UNIT;
            const long kc = (long)(h + 2) * 32;
            GLD(aS + kc,            wU + wave * 1024);
            GLD(aS + 16 * lda + kc, wU + wave * 1024 + 512);
            GLD(bS + kc,            wU + AUNIT + wave * 1024);
            GLD(bS + 16 * ldb + kc, wU + AUNIT + wave * 1024 + 512);
        }
        SCHED0;
        WAIT_LGKM0;
        SCHED0;
        __builtin_amdgcn_s_setprio(1);
#pragma unroll
        for (int i = 0; i < 4; ++i)
#pragma unroll
            for (int j = 0; j < 4; ++j)
                acc[i][j] = __builtin_amdgcn_mfma_f32_16x16x32_bf16(af[i], bf[j], acc[i][j], 0, 0, 0);
        __builtin_amdgcn_s_setprio(0);
        SCHED0;
        if (h < NHALF - 2) WAIT_VM(4);
        else               WAIT_VM(0);
        SCHED0;
        MEMFENCE;
        __builtin_amdgcn_s_barrier();
        SCHED0;

        cu = (cu == 2) ? 0 : cu + 1;
        su = (su == 2) ? 0 : su + 1;
    }

    // ---- epilogue (proven m97 C-layout) ----
#pragma unroll
    for (int i = 0; i < 4; ++i)
#pragma unroll
        for (int j = 0; j < 4; ++j)
#pragma unroll
            for (int r = 0; r < 4; ++r) {
                int row = bm + wm + i * 16 + quad * 4 + r;
                int col = bn + wn + j * 16 + l15;
                if (c_f32)
                    ((float*)C)[(long)row * ldc + col] = acc[i][j][r];
                else
                    ((__bf16*)C)[(long)row * ldc + col] = (__bf16)acc[i][j][r];
            }
}

// ---------------- ring-3 pipelined 64x128 GEMM (gemm2) ---------------------
// R12: gemm2 was ~65-70us for 17.2 GFLOP — 512 blocks = only 2 blocks/CU
// resident (same parallelism-starvation class as R8). N=1024 caps bn-tiles
// at 8, so shrink BM: 64x128 tile, 4 waves (2x2 of 32x64, acc[2][4]),
// grid = 128 bm x 8 bn = 1024 blocks = exactly 4/CU. LDS ring of 3 units
// {A[64][32], B[128][32]} = 36 KiB -> 4 blocks/CU (144 <= 160 KiB).
// 3 GLDs/unit (A 1 + B 2) -> counted vmcnt(3) steady, tail 0. Same
// swizzle pair and C-layout as gemm_p3. XCD decode: xcd owns 16
// consecutive bm-tiles (1 MB A panel, L2-resident).
__global__ __launch_bounds__(256, 4)
void gemm_p3n(const __bf16* __restrict__ A, long lda,
              const __bf16* __restrict__ Bt, long ldb,
              void* __restrict__ C, long ldc, int c_f32, int K) {
    constexpr int AUNIT = 64 * 32;           // 2048 elems = 4 KiB
    constexpr int BUNIT = 128 * 32;          // 4096 elems = 8 KiB
    constexpr int UNIT  = AUNIT + BUNIT;     // 12 KiB
    __shared__ __align__(16) __bf16 lds[3 * UNIT];   // 36 KiB

    const int tid  = threadIdx.x;
    const int lane = tid & 63;
    const int wave = tid >> 6;               // 0..3
    const int l15  = lane & 15;
    const int quad = lane >> 4;

    const int wg   = blockIdx.x;
    const int xcd  = wg & 7;
    const int idx  = wg >> 3;                // 0..127
    const int bm   = (xcd * 16 + (idx & 15)) * 64;
    const int bn   = (idx >> 4) * 128;

    const int wm = (wave & 1) * 32;
    const int wn = (wave >> 1) * 64;

    f32x4 zero = {0.f, 0.f, 0.f, 0.f};
    f32x4 acc[2][4];
#pragma unroll
    for (int i = 0; i < 2; ++i)
#pragma unroll
        for (int j = 0; j < 4; ++j) acc[i][j] = zero;

    const int srow  = lane >> 2;             // 0..15
    const int swcol = ((lane & 3) ^ ((lane >> 3) & 3)) * 8;
    const __bf16* aS = A  + (long)(bm + wave * 16 + srow) * lda + swcol;
    const __bf16* bS = Bt + (long)(bn + wave * 32 + srow) * ldb + swcol;

    const int rcol = (quad ^ ((l15 >> 1) & 3)) * 8;

    const int NHALF = K >> 5;

    // ---- prologue: stage units 0,1 (3 GLDs/wave each) ----
#pragma unroll
    for (int u = 0; u < 2; ++u) {
        __bf16* wU = lds + u * UNIT;
        const long kc = (long)u * 32;
        GLD(aS + kc,            wU + wave * 512);
        GLD(bS + kc,            wU + AUNIT + wave * 1024);
        GLD(bS + 16 * ldb + kc, wU + AUNIT + wave * 1024 + 512);
    }
    SCHED0;
    WAIT_VM(3);               // unit 0 resident, unit 1 in flight
    SCHED0;
    __builtin_amdgcn_s_barrier();
    SCHED0;

    int cu = 0;
    int su = 2;
    for (int h = 0; h < NHALF; ++h) {
        const __bf16* uA = lds + cu * UNIT;
        const __bf16* uB = uA + AUNIT;

        bf16x8 af[2], bf[4];
#pragma unroll
        for (int i = 0; i < 2; ++i)
            af[i] = *(const bf16x8*)(uA + (wm + i * 16 + l15) * 32 + rcol);
#pragma unroll
        for (int j = 0; j < 4; ++j)
            bf[j] = *(const bf16x8*)(uB + (wn + j * 16 + l15) * 32 + rcol);

        if (h + 2 < NHALF) {
            __bf16* wU = lds + su * UNIT;
            const long kc = (long)(h + 2) * 32;
            GLD(aS + kc,            wU + wave * 512);
            GLD(bS + kc,            wU + AUNIT + wave * 1024);
            GLD(bS + 16 * ldb + kc, wU + AUNIT + wave * 1024 + 512);
        }
        SCHED0;
        WAIT_LGKM0;
        SCHED0;
        __builtin_amdgcn_s_setprio(1);
#pragma unroll
        for (int i = 0; i < 2; ++i)
#pragma unroll
            for (int j = 0; j < 4; ++j)
                acc[i][j] = __builtin_amdgcn_mfma_f32_16x16x32_bf16(af[i], bf[j], acc[i][j], 0, 0, 0);
        __builtin_amdgcn_s_setprio(0);
        SCHED0;
        if (h < NHALF - 2) WAIT_VM(3);
        else               WAIT_VM(0);
        SCHED0;
        MEMFENCE;
        __builtin_amdgcn_s_barrier();
        SCHED0;

        cu = (cu == 2) ? 0 : cu + 1;
        su = (su == 2) ? 0 : su + 1;
    }

    // ---- epilogue ----
#pragma unroll
    for (int i = 0; i < 2; ++i)
#pragma unroll
        for (int j = 0; j < 4; ++j)
#pragma unroll
            for (int r = 0; r < 4; ++r) {
                int row = bm + wm + i * 16 + quad * 4 + r;
                int col = bn + wn + j * 16 + l15;
                if (c_f32)
                    ((float*)C)[(long)row * ldc + col] = acc[i][j][r];
                else
                    ((__bf16*)C)[(long)row * ldc + col] = (__bf16)acc[i][j][r];
            }
}

// ---------------- GEMM fallback (dtype-flex) — used if ws < 72 MB ----------
__global__ __launch_bounds__(256)
void gemm_bn(const void* __restrict__ A, long lda, long a0, int a_flex,
             const void* __restrict__ B, long ldb, int b_flex,
             void* __restrict__ C, long ldc, int c_flex, int K,
             const unsigned short* __restrict__ probe) {
    __shared__ __align__(16) __bf16 sA[128 * 32];
    __shared__ __align__(16) __bf16 sB[128 * 32];
    const int tid  = threadIdx.x;
    const int lane = tid & 63;
    const int wave = tid >> 6;
    const int l15  = lane & 15;
    const int quad = lane >> 4;
    const int bm = blockIdx.y * 128;
    const int bn = blockIdx.x * 128;
    const int wm = (wave & 1) * 64;
    const int wn = (wave >> 1) * 64;

    const bool is_f32 = detect_f32(probe, lane);
    const bool a_f32 = a_flex && is_f32;
    const bool b_f32 = b_flex && is_f32;
    const bool c_f32 = c_flex && is_f32;

    f32x4 zero = {0.f, 0.f, 0.f, 0.f};
    f32x4 acc[4][4];
#pragma unroll
    for (int i = 0; i < 4; ++i)
#pragma unroll
        for (int j = 0; j < 4; ++j) acc[i][j] = zero;

    const int srow = tid >> 2;
    const int scol = (tid & 3) * 8;

    for (int k0 = 0; k0 < K; k0 += 32) {
        __syncthreads();
        *(bf16x8*)(sA + tid * 8) =
            load8_flex(A, a0 + (long)(bm + srow) * lda + k0 + scol, a_f32);
        *(bf16x8*)(sA + 2048 + tid * 8) =
            load8_flex(A, a0 + (long)(bm + 64 + srow) * lda + k0 + scol, a_f32);
#pragma unroll
        for (int it = 0; it < 2; ++it) {
            int idx = tid + it * 256;
            int kk  = idx & 31;
            int n8  = (idx >> 5) * 8;
            bf16x8 bv = load8_flex(B, (long)(k0 + kk) * ldb + bn + n8, b_f32);
#pragma unroll
            for (int jj = 0; jj < 8; ++jj) sB[(n8 + jj) * 32 + kk] = bv[jj];
        }
        __syncthreads();

        bf16x8 af[4], bfm[4];
#pragma unroll
        for (int i = 0; i < 4; ++i)
            af[i] = *(const bf16x8*)(sA + (wm + i * 16 + l15) * 32 + quad * 8);
#pragma unroll
        for (int j = 0; j < 4; ++j)
            bfm[j] = *(const bf16x8*)(sB + (wn + j * 16 + l15) * 32 + quad * 8);
#pragma unroll
        for (int i = 0; i < 4; ++i)
#pragma unroll
            for (int j = 0; j < 4; ++j)
                acc[i][j] = __builtin_amdgcn_mfma_f32_16x16x32_bf16(af[i], bfm[j], acc[i][j], 0, 0, 0);
    }

#pragma unroll
    for (int i = 0; i < 4; ++i)
#pragma unroll
        for (int j = 0; j < 4; ++j)
#pragma unroll
            for (int r = 0; r < 4; ++r) {
                int row = bm + wm + i * 16 + quad * 4 + r;
                int col = bn + wn + j * 16 + l15;
                if (c_f32)
                    ((float*)C)[(long)row * ldc + col] = acc[i][j][r];
                else
                    ((__bf16*)C)[(long)row * ldc + col] = (__bf16)acc[i][j][r];
            }
}

// ---------------- flash attention (causal) v7b: unchanged from R11 ---------
// R11 post-mortem: grid 1024 + lut was NEUTRAL (dur 86.6, occupancy stuck
// ~37%) — attn is CU-throughput-bound (VALU 40% softmax path + 18% LDS
// conflicts + MFMA 18%), not latency-bound. Keeping this version; the next
// attn lever would be in-register P (T12), a large rewrite.
__global__ __launch_bounds__(512, 4)
void attn_k(__bf16* __restrict__ qkvp, int bhbits) {
    const int bid  = blockIdx.x;
    const int g    = bid >> bhbits;              // group 0..15
    const int bh   = bid & ((1 << bhbits) - 1);
    const int h    = bh & 15;
    const int b    = bh >> 4;
    const int tid  = threadIdx.x;
    const int lane = tid & 63;
    const int wave = tid >> 6;          // 0..7
    const int l15  = lane & 15;
    const int quad = lane >> 4;

    // balanced group->qt map: quartile sums of qt all = 30 (nk sums = 68)
    const int gm = g & 12;
    const int qt = (gm == 0) ? (15 - g)
                 : (gm == 4) ? (g + 4)
                 : (gm == 8) ? (15 - g)
                 :             (g - 12);

    __shared__ __align__(16) __bf16 sK[64 * 72];    // [tk][dh] stride 72
    __shared__ __align__(16) __bf16 sVT[64 * 64];   // [dh][rot(tk)]
    __shared__ __align__(16) __bf16 sP[8][16 * 64]; // [wave][q][rot(k)]

    const long rs = 3 * DM;
    __bf16* base = qkvp + (long)b * T_SEQ * rs + h * DH;

    // staging: one 8B chunk per thread (512 threads cover 64 rows x 8 chunks)
    const int sr  = tid >> 3;           // 0..63
    const int sm  = tid & 7;
    const int sc8 = sm * 8;
    const int rot = 8 * ((5 * sm) & 7);
    const int vcol = (sr + rot) & 63;

    bf16x8 vone;
#pragma unroll
    for (int jj = 0; jj < 8; ++jj) vone[jj] = (__bf16)1.0f;

    f32x4 zero = {0.f, 0.f, 0.f, 0.f};

    const int q0  = qt * 128;
    const int wq0 = q0 + wave * 16;
    const int nk  = (q0 + 128) >> 6;          // = 2*qt + 2

    // Q fragments (A-layout), pre-scaled by 0.125*log2(e) for exp2
    const float qscale = 0.125f * 1.44269504089f;
    bf16x8 qa[2];
#pragma unroll
    for (int kk = 0; kk < 2; ++kk) {
        bf16x8 v = *(const bf16x8*)(base + (long)(wq0 + l15) * rs + kk * 32 + quad * 8);
#pragma unroll
        for (int jj = 0; jj < 8; ++jj) v[jj] = (__bf16)((float)v[jj] * qscale);
        qa[kk] = v;
    }

    f32x4 o[4], o4;
    o4 = zero;
#pragma unroll
    for (int j = 0; j < 4; ++j) o[j] = zero;

    // prefetch tile 0 into registers
    bf16x8 kreg, vreg;
    {
        const __bf16* rp = base + (long)sr * rs;
        kreg = *(const bf16x8*)(rp + DM + sc8);
        vreg = *(const bf16x8*)(rp + 2 * DM + sc8);
    }

    for (int t = 0; t < nk; ++t) {
        const int k0 = t * 64;
        __syncthreads();                 // prior tile's LDS reads done
        *(bf16x8*)(sK + sr * 72 + sc8) = kreg;
#pragma unroll
        for (int jj = 0; jj < 8; ++jj)
            sVT[(sc8 + jj) * 64 + vcol] = vreg[jj];
        __syncthreads();                 // staging visible

        // prefetch tile t+1 (vmcnt stays outstanding through compute)
        if (t + 1 < nk) {
            const __bf16* rp = base + (long)(k0 + 64 + sr) * rs;
            kreg = *(const bf16x8*)(rp + DM + sc8);
            vreg = *(const bf16x8*)(rp + 2 * DM + sc8);
        }

        const bool active = (k0 <= wq0 + 15);
        if (active) {
            f32x4 s[4];
#pragma unroll
            for (int j = 0; j < 4; ++j) s[j] = zero;
#pragma unroll
            for (int kk = 0; kk < 2; ++kk) {
                bf16x8 kb[4];
#pragma unroll
                for (int j = 0; j < 4; ++j)
                    kb[j] = *(const bf16x8*)(sK + (j * 16 + l15) * 72 + kk * 32 + quad * 8);
#pragma unroll
                for (int j = 0; j < 4; ++j)
                    s[j] = __builtin_amdgcn_mfma_f32_16x16x32_bf16(qa[kk], kb[j], s[j], 0, 0, 0);
            }

            const bool needmask = (k0 + 63 > wq0);   // wave-uniform
#pragma unroll
            for (int r = 0; r < 4; ++r) {
                const int qg = wq0 + quad * 4 + r;
#pragma unroll
                for (int j = 0; j < 4; ++j) {
                    const int kg = k0 + j * 16 + l15;
                    float pv = EXP2(fminf(s[j][r], 86.f));
                    if (needmask) pv = (kg > qg) ? 0.f : pv;
                    sP[wave][(quad * 4 + r) * 64 +
                             ((j * 16 + l15 + 16 * quad) & 63)] = (__bf16)pv;
                }
            }
        }

        // sP is wave-private: wave-local LDS drain (lgkm only, vmcnt alive)
        SCHED0;
        WAIT_LGKM0;
        SCHED0;

        if (active) {
#pragma unroll
            for (int kk = 0; kk < 2; ++kk) {
                bf16x8 pa, vb[4];
                pa = *(const bf16x8*)(
                    &sP[wave][l15 * 64 +
                              ((kk * 32 + quad * 8 + 16 * (l15 >> 2)) & 63)]);
#pragma unroll
                for (int j = 0; j < 4; ++j) {
                    const int gg = (2 * j + (l15 >> 3)) & 7;
                    vb[j] = *(const bf16x8*)(
                        sVT + (j * 16 + l15) * 64 +
                        ((kk * 32 + quad * 8 + 8 * ((5 * gg) & 7)) & 63));
                }
#pragma unroll
                for (int j = 0; j < 4; ++j)
                    o[j] = __builtin_amdgcn_mfma_f32_16x16x32_bf16(pa, vb[j], o[j], 0, 0, 0);
                o4 = __builtin_amdgcn_mfma_f32_16x16x32_bf16(pa, vone, o4, 0, 0, 0);
            }
        }
    }

    // epilogue: l = o4[r] (all cols equal); no shuffles needed
#pragma unroll
    for (int r = 0; r < 4; ++r) {
        const int qg  = wq0 + quad * 4 + r;
        const float inv = 1.f / o4[r];
#pragma unroll
        for (int j = 0; j < 4; ++j)
            base[(long)qg * rs + j * 16 + l15] = (__bf16)(o[j][r] * inv);
    }
}

// ---------------- diagnostic fallback (ws too small) ----------------
__global__ __launch_bounds__(256)
void fallback_k(float* __restrict__ out, long n, float wsmb) {
    long i = (long)blockIdx.x * blockDim.x + threadIdx.x;
    for (; i < n; i += (long)gridDim.x * blockDim.x) out[i] = 0.f;
    if (blockIdx.x == 0 && threadIdx.x == 0) out[0] = wsmb;
}

extern "C" void kernel_launch(void* const* d_in, const int* in_sizes, int n_in,
                              void* d_out, int out_size, void* d_ws, size_t ws_size,
                              hipStream_t stream) {
    const void* x     = d_in[0];   // [8192][1024] fp32
    const void* w_qkv = d_in[1];   // [1024][3072] fp32
    const void* w_out = d_in[2];   // [1024][1024] fp32
    const unsigned short* probe = (const unsigned short*)d_in[0];

    __bf16* qkv = (__bf16*)d_ws;                       // 48 MB
    __bf16* xb  = qkv + (size_t)8192 * 3072;           // +16 MB
    __bf16* wtq = xb  + (size_t)8192 * 1024;           // +6 MB
    __bf16* wto = wtq + (size_t)3072 * 1024;           // +2 MB  => 72 MB

    const size_t NEED_T1   = (size_t)72 * 1024 * 1024;
    const size_t NEED_FULL = (size_t)8192 * 3072 * 2;  // 48 MB
    const size_t NEED_B    = (size_t)2048 * 3072 * 2;  // 12 MB

    if (ws_size >= NEED_T1) {
        cvt_x<<<dim3(4096), 256, 0, stream>>>((const float*)x, xb, (long)8192 * 1024 / 8);
        tpose_cvt<<<dim3(96, 32), 256, 0, stream>>>((const float*)w_qkv, wtq, 1024, 3072);
        tpose_cvt<<<dim3(32, 32), 256, 0, stream>>>((const float*)w_out, wto, 1024, 1024);
        // gemm1: 64 bm x 24 bn = 1536 blocks, 3/CU co-resident stream
        gemm_p3<<<dim3(1536), 256, 0, stream>>>(xb, 1024, wtq, 1024, qkv, 3072, 0, 1024);
        // attn: 16 groups x 64 bh = 1024 blocks, lut-balanced
        attn_k<<<dim3(16 * 64), 512, 0, stream>>>(qkv, 6);
        // gemm2: 64x128 tile, 128 bm x 8 bn = 1024 blocks = 4/CU
        gemm_p3n<<<dim3(1024), 256, 0, stream>>>(qkv, 3072, wto, 1024, d_out, 1024, 1, 1024);
    } else if (ws_size >= NEED_FULL) {
        gemm_bn<<<dim3(24, 64), 256, 0, stream>>>(
            x, 1024, 0, 1, w_qkv, 3072, 1, qkv, 3072, 0, 1024, probe);
        attn_k<<<dim3(16 * 64), 512, 0, stream>>>(qkv, 6);
        gemm_bn<<<dim3(8, 64), 256, 0, stream>>>(
            qkv, 3072, 0, 0, w_out, 1024, 1, d_out, 1024, 1, 1024, probe);
    } else if (ws_size >= NEED_B) {
        for (int b = 0; b < NB; ++b) {
            long xoff = (long)b * T_SEQ * DM;
            gemm_bn<<<dim3(24, 16), 256, 0, stream>>>(
                x, 1024, xoff, 1, w_qkv, 3072, 1, qkv, 3072, 0, 1024, probe);
            attn_k<<<dim3(16 * 16), 512, 0, stream>>>(qkv, 4);
            gemm_bn<<<dim3(8, 16), 256, 0, stream>>>(
                qkv, 3072, 0, 0, w_out, 1024, 1,
                (void*)((char*)d_out + (size_t)b * T_SEQ * DM * 4),
                1024, 1, 1024, probe);
        }
    } else {
        fallback_k<<<dim3(512), 256, 0, stream>>>(
            (float*)d_out, (long)8192 * 1024, (float)(ws_size >> 20));
    }
}

// Round 13
// 253.980 us; speedup vs baseline: 1.0233x; 1.0233x over previous
//
#include <hip/hip_runtime.h>
#include <math.h>

#define T_SEQ 2048
#define NB 4
#define NH 16
#define DH 64
#define DM 1024

typedef __attribute__((ext_vector_type(8))) __bf16 bf16x8;
typedef __attribute__((ext_vector_type(4))) float f32x4;

typedef const __attribute__((address_space(1))) void* gas_t;
typedef __attribute__((address_space(3))) void* las_t;

#if __has_builtin(__builtin_amdgcn_exp2f)
#define EXP2(x) __builtin_amdgcn_exp2f(x)
#else
#define EXP2(x) __expf((x) * 0.69314718056f)
#endif

#define SCHED0 __builtin_amdgcn_sched_barrier(0)
#define GLD(src, dst) __builtin_amdgcn_global_load_lds((gas_t)(src), (las_t)(dst), 16, 0, 0)
#define WAIT_VM(N) asm volatile("s_waitcnt vmcnt(" #N ")" ::: "memory")
#define WAIT_LGKM0 asm volatile("s_waitcnt lgkmcnt(0)" ::: "memory")
#define MEMFENCE   asm volatile("" ::: "memory")

// ---- dtype detection (kept for fallback tiers)
__device__ inline bool detect_f32(const unsigned short* probe, int lane) {
    unsigned short u = probe[lane];
    int e = (u >> 7) & 0xFF;
    bool outlier = (e >= 140) || (e <= 90 && (u & 0x7fff) != 0);
    unsigned long long m = __ballot(outlier);
    return __popcll(m) >= 4;
}

__device__ inline bf16x8 load8_flex(const void* base, long elem, bool f32) {
    if (!f32) {
        return *(const bf16x8*)((const __bf16*)base + elem);
    } else {
        const float* f = (const float*)base + elem;
        float4 a = *(const float4*)f;
        float4 b = *(const float4*)(f + 4);
        bf16x8 r;
        r[0] = (__bf16)a.x; r[1] = (__bf16)a.y; r[2] = (__bf16)a.z; r[3] = (__bf16)a.w;
        r[4] = (__bf16)b.x; r[5] = (__bf16)b.y; r[6] = (__bf16)b.z; r[7] = (__bf16)b.w;
        return r;
    }
}

// ---------------- fp32 -> bf16 elementwise convert -------------------------
__global__ __launch_bounds__(256)
void cvt_x(const float* __restrict__ in, __bf16* __restrict__ out, long n8) {
    long i = (long)blockIdx.x * blockDim.x + threadIdx.x;
    if (i >= n8) return;
    const float* f = in + i * 8;
    float4 a = *(const float4*)f;
    float4 b = *(const float4*)(f + 4);
    bf16x8 r;
    r[0] = (__bf16)a.x; r[1] = (__bf16)a.y; r[2] = (__bf16)a.z; r[3] = (__bf16)a.w;
    r[4] = (__bf16)b.x; r[5] = (__bf16)b.y; r[6] = (__bf16)b.z; r[7] = (__bf16)b.w;
    *(bf16x8*)(out + i * 8) = r;
}

// ---------------- fp32 [R][C] -> bf16 [C][R] transpose+convert -------------
__global__ __launch_bounds__(256)
void tpose_cvt(const float* __restrict__ in, __bf16* __restrict__ out, int R, int C) {
    __shared__ __bf16 tile[32][33];
    const int bx = blockIdx.x * 32;
    const int by = blockIdx.y * 32;
    const int tx = threadIdx.x & 31;
    const int ty = threadIdx.x >> 5;
#pragma unroll
    for (int it = 0; it < 4; ++it) {
        int r = ty + it * 8;
        tile[r][tx] = (__bf16)in[(long)(by + r) * C + bx + tx];
    }
    __syncthreads();
#pragma unroll
    for (int it = 0; it < 4; ++it) {
        int r = ty + it * 8;
        out[(long)(bx + r) * R + by + tx] = tile[tx][r];
    }
}

// ---------------- ring-3 pipelined 128x128 GEMM (both GEMMs) ---------------
// R9 structure, unchanged. R12's 64x128 gemm2 reshape was null-to-negative
// (smaller MFMA cluster per barrier = worse per-block efficiency); reverted.
__global__ __launch_bounds__(256, 3)
void gemm_p3(const __bf16* __restrict__ A, long lda,
             const __bf16* __restrict__ Bt, long ldb,
             void* __restrict__ C, long ldc, int c_f32, int K) {
    constexpr int AUNIT = 128 * 32;          // 4096 elems = 8 KiB
    constexpr int UNIT  = 2 * AUNIT;         // A + B = 16 KiB
    __shared__ __align__(16) __bf16 lds[3 * UNIT];   // 48 KiB

    const int tid  = threadIdx.x;
    const int lane = tid & 63;
    const int wave = tid >> 6;               // 0..3
    const int l15  = lane & 15;
    const int quad = lane >> 4;

    const int wg   = blockIdx.x;
    const int xcd  = wg & 7;
    const int idx  = wg >> 3;
    const int bm   = (xcd * 8 + (idx & 7)) * 128;
    const int bn   = (idx >> 3) * 128;

    const int wm = (wave & 1) * 64;
    const int wn = (wave >> 1) * 64;

    f32x4 zero = {0.f, 0.f, 0.f, 0.f};
    f32x4 acc[4][4];
#pragma unroll
    for (int i = 0; i < 4; ++i)
#pragma unroll
        for (int j = 0; j < 4; ++j) acc[i][j] = zero;

    const int srow  = lane >> 2;             // 0..15
    const int swcol = ((lane & 3) ^ ((lane >> 3) & 3)) * 8;
    const __bf16* aS = A  + (long)(bm + wave * 32 + srow) * lda + swcol;
    const __bf16* bS = Bt + (long)(bn + wave * 32 + srow) * ldb + swcol;

    const int rcol = (quad ^ ((l15 >> 1) & 3)) * 8;

    const int NHALF = K >> 5;

    // ---- prologue: stage units 0,1 ----
#pragma unroll
    for (int u = 0; u < 2; ++u) {
        __bf16* wU = lds + u * UNIT;
        const long kc = (long)u * 32;
        GLD(aS + kc,            wU + wave * 1024);
        GLD(aS + 16 * lda + kc, wU + wave * 1024 + 512);
        GLD(bS + kc,            wU + AUNIT + wave * 1024);
        GLD(bS + 16 * ldb + kc, wU + AUNIT + wave * 1024 + 512);
    }
    SCHED0;
    WAIT_VM(4);
    SCHED0;
    __builtin_amdgcn_s_barrier();
    SCHED0;

    int cu = 0;
    int su = 2;
    for (int h = 0; h < NHALF; ++h) {
        const __bf16* uA = lds + cu * UNIT;
        const __bf16* uB = uA + AUNIT;

        bf16x8 af[4], bf[4];
#pragma unroll
        for (int i = 0; i < 4; ++i)
            af[i] = *(const bf16x8*)(uA + (wm + i * 16 + l15) * 32 + rcol);
#pragma unroll
        for (int j = 0; j < 4; ++j)
            bf[j] = *(const bf16x8*)(uB + (wn + j * 16 + l15) * 32 + rcol);

        if (h + 2 < NHALF) {
            __bf16* wU = lds + su * UNIT;
            const long kc = (long)(h + 2) * 32;
            GLD(aS + kc,            wU + wave * 1024);
            GLD(aS + 16 * lda + kc, wU + wave * 1024 + 512);
            GLD(bS + kc,            wU + AUNIT + wave * 1024);
            GLD(bS + 16 * ldb + kc, wU + AUNIT + wave * 1024 + 512);
        }
        SCHED0;
        WAIT_LGKM0;
        SCHED0;
        __builtin_amdgcn_s_setprio(1);
#pragma unroll
        for (int i = 0; i < 4; ++i)
#pragma unroll
            for (int j = 0; j < 4; ++j)
                acc[i][j] = __builtin_amdgcn_mfma_f32_16x16x32_bf16(af[i], bf[j], acc[i][j], 0, 0, 0);
        __builtin_amdgcn_s_setprio(0);
        SCHED0;
        if (h < NHALF - 2) WAIT_VM(4);
        else               WAIT_VM(0);
        SCHED0;
        MEMFENCE;
        __builtin_amdgcn_s_barrier();
        SCHED0;

        cu = (cu == 2) ? 0 : cu + 1;
        su = (su == 2) ? 0 : su + 1;
    }

    // ---- epilogue (proven m97 C-layout) ----
#pragma unroll
    for (int i = 0; i < 4; ++i)
#pragma unroll
        for (int j = 0; j < 4; ++j)
#pragma unroll
            for (int r = 0; r < 4; ++r) {
                int row = bm + wm + i * 16 + quad * 4 + r;
                int col = bn + wn + j * 16 + l15;
                if (c_f32)
                    ((float*)C)[(long)row * ldc + col] = acc[i][j][r];
                else
                    ((__bf16*)C)[(long)row * ldc + col] = (__bf16)acc[i][j][r];
            }
}

// ---------------- GEMM fallback (dtype-flex) — used if ws < 72 MB ----------
__global__ __launch_bounds__(256)
void gemm_bn(const void* __restrict__ A, long lda, long a0, int a_flex,
             const void* __restrict__ B, long ldb, int b_flex,
             void* __restrict__ C, long ldc, int c_flex, int K,
             const unsigned short* __restrict__ probe) {
    __shared__ __align__(16) __bf16 sA[128 * 32];
    __shared__ __align__(16) __bf16 sB[128 * 32];
    const int tid  = threadIdx.x;
    const int lane = tid & 63;
    const int wave = tid >> 6;
    const int l15  = lane & 15;
    const int quad = lane >> 4;
    const int bm = blockIdx.y * 128;
    const int bn = blockIdx.x * 128;
    const int wm = (wave & 1) * 64;
    const int wn = (wave >> 1) * 64;

    const bool is_f32 = detect_f32(probe, lane);
    const bool a_f32 = a_flex && is_f32;
    const bool b_f32 = b_flex && is_f32;
    const bool c_f32 = c_flex && is_f32;

    f32x4 zero = {0.f, 0.f, 0.f, 0.f};
    f32x4 acc[4][4];
#pragma unroll
    for (int i = 0; i < 4; ++i)
#pragma unroll
        for (int j = 0; j < 4; ++j) acc[i][j] = zero;

    const int srow = tid >> 2;
    const int scol = (tid & 3) * 8;

    for (int k0 = 0; k0 < K; k0 += 32) {
        __syncthreads();
        *(bf16x8*)(sA + tid * 8) =
            load8_flex(A, a0 + (long)(bm + srow) * lda + k0 + scol, a_f32);
        *(bf16x8*)(sA + 2048 + tid * 8) =
            load8_flex(A, a0 + (long)(bm + 64 + srow) * lda + k0 + scol, a_f32);
#pragma unroll
        for (int it = 0; it < 2; ++it) {
            int idx = tid + it * 256;
            int kk  = idx & 31;
            int n8  = (idx >> 5) * 8;
            bf16x8 bv = load8_flex(B, (long)(k0 + kk) * ldb + bn + n8, b_f32);
#pragma unroll
            for (int jj = 0; jj < 8; ++jj) sB[(n8 + jj) * 32 + kk] = bv[jj];
        }
        __syncthreads();

        bf16x8 af[4], bfm[4];
#pragma unroll
        for (int i = 0; i < 4; ++i)
            af[i] = *(const bf16x8*)(sA + (wm + i * 16 + l15) * 32 + quad * 8);
#pragma unroll
        for (int j = 0; j < 4; ++j)
            bfm[j] = *(const bf16x8*)(sB + (wn + j * 16 + l15) * 32 + quad * 8);
#pragma unroll
        for (int i = 0; i < 4; ++i)
#pragma unroll
            for (int j = 0; j < 4; ++j)
                acc[i][j] = __builtin_amdgcn_mfma_f32_16x16x32_bf16(af[i], bfm[j], acc[i][j], 0, 0, 0);
    }

#pragma unroll
    for (int i = 0; i < 4; ++i)
#pragma unroll
        for (int j = 0; j < 4; ++j)
#pragma unroll
            for (int r = 0; r < 4; ++r) {
                int row = bm + wm + i * 16 + quad * 4 + r;
                int col = bn + wn + j * 16 + l15;
                if (c_f32)
                    ((float*)C)[(long)row * ldc + col] = acc[i][j][r];
                else
                    ((__bf16*)C)[(long)row * ldc + col] = (__bf16)acc[i][j][r];
            }
}

// ---------------- flash attention (causal) v8: conflict-free sVT/sP --------
// R13: the 9.73M SQ_LDS_BANK_CONFLICT traced analytically to sVT PV-reads:
// col depends only on (quad, l15>>3), so the 8 lanes sharing it read the
// SAME column at different rows; row stride 64 elem = 128 B = 0 mod 32 dw
// -> all 8 on the same 4 banks for every dword phase = guaranteed 8-way
// conflict on all 8 sVT reads per tile-wave (and 4-way on the sP pa read).
// Fix: pad sVT and sP row strides 64 -> 72 elems (144 B = 36 dw) — bank
// gains a 4*l15 term; the col-sharing lanes (l15 mod 8 = 0..7) spread to 8
// distinct bank groups -> conflict-free. Write-side patterns re-derived
// under stride 72: sVT staging (288*sm = 0 mod 32, rot still spreads cols)
// and sP writes stay <=2 lanes/bank. All col formulas unchanged.
// LDS 33792 -> 36864 B. Everything else identical to R11's v7b.
#define SVS 72   // sVT/sP padded row stride (elements)
__global__ __launch_bounds__(512, 4)
void attn_k(__bf16* __restrict__ qkvp, int bhbits) {
    const int bid  = blockIdx.x;
    const int g    = bid >> bhbits;              // group 0..15
    const int bh   = bid & ((1 << bhbits) - 1);
    const int h    = bh & 15;
    const int b    = bh >> 4;
    const int tid  = threadIdx.x;
    const int lane = tid & 63;
    const int wave = tid >> 6;          // 0..7
    const int l15  = lane & 15;
    const int quad = lane >> 4;

    // balanced group->qt map: quartile sums of qt all = 30 (nk sums = 68)
    const int gm = g & 12;
    const int qt = (gm == 0) ? (15 - g)
                 : (gm == 4) ? (g + 4)
                 : (gm == 8) ? (15 - g)
                 :             (g - 12);

    __shared__ __align__(16) __bf16 sK[64 * 72];      // [tk][dh] stride 72
    __shared__ __align__(16) __bf16 sVT[64 * SVS];    // [dh][rot(tk)] stride 72
    __shared__ __align__(16) __bf16 sP[8][16 * SVS];  // [wave][q][rot(k)] stride 72

    const long rs = 3 * DM;
    __bf16* base = qkvp + (long)b * T_SEQ * rs + h * DH;

    // staging: one 8B chunk per thread (512 threads cover 64 rows x 8 chunks)
    const int sr  = tid >> 3;           // 0..63
    const int sm  = tid & 7;
    const int sc8 = sm * 8;
    const int rot = 8 * ((5 * sm) & 7);
    const int vcol = (sr + rot) & 63;

    bf16x8 vone;
#pragma unroll
    for (int jj = 0; jj < 8; ++jj) vone[jj] = (__bf16)1.0f;

    f32x4 zero = {0.f, 0.f, 0.f, 0.f};

    const int q0  = qt * 128;
    const int wq0 = q0 + wave * 16;
    const int nk  = (q0 + 128) >> 6;          // = 2*qt + 2

    // Q fragments (A-layout), pre-scaled by 0.125*log2(e) for exp2
    const float qscale = 0.125f * 1.44269504089f;
    bf16x8 qa[2];
#pragma unroll
    for (int kk = 0; kk < 2; ++kk) {
        bf16x8 v = *(const bf16x8*)(base + (long)(wq0 + l15) * rs + kk * 32 + quad * 8);
#pragma unroll
        for (int jj = 0; jj < 8; ++jj) v[jj] = (__bf16)((float)v[jj] * qscale);
        qa[kk] = v;
    }

    f32x4 o[4], o4;
    o4 = zero;
#pragma unroll
    for (int j = 0; j < 4; ++j) o[j] = zero;

    // prefetch tile 0 into registers
    bf16x8 kreg, vreg;
    {
        const __bf16* rp = base + (long)sr * rs;
        kreg = *(const bf16x8*)(rp + DM + sc8);
        vreg = *(const bf16x8*)(rp + 2 * DM + sc8);
    }

    for (int t = 0; t < nk; ++t) {
        const int k0 = t * 64;
        __syncthreads();                 // prior tile's LDS reads done
        *(bf16x8*)(sK + sr * 72 + sc8) = kreg;
#pragma unroll
        for (int jj = 0; jj < 8; ++jj)
            sVT[(sc8 + jj) * SVS + vcol] = vreg[jj];
        __syncthreads();                 // staging visible

        // prefetch tile t+1 (vmcnt stays outstanding through compute)
        if (t + 1 < nk) {
            const __bf16* rp = base + (long)(k0 + 64 + sr) * rs;
            kreg = *(const bf16x8*)(rp + DM + sc8);
            vreg = *(const bf16x8*)(rp + 2 * DM + sc8);
        }

        const bool active = (k0 <= wq0 + 15);
        if (active) {
            f32x4 s[4];
#pragma unroll
            for (int j = 0; j < 4; ++j) s[j] = zero;
#pragma unroll
            for (int kk = 0; kk < 2; ++kk) {
                bf16x8 kb[4];
#pragma unroll
                for (int j = 0; j < 4; ++j)
                    kb[j] = *(const bf16x8*)(sK + (j * 16 + l15) * 72 + kk * 32 + quad * 8);
#pragma unroll
                for (int j = 0; j < 4; ++j)
                    s[j] = __builtin_amdgcn_mfma_f32_16x16x32_bf16(qa[kk], kb[j], s[j], 0, 0, 0);
            }

            const bool needmask = (k0 + 63 > wq0);   // wave-uniform
#pragma unroll
            for (int r = 0; r < 4; ++r) {
                const int qg = wq0 + quad * 4 + r;
#pragma unroll
                for (int j = 0; j < 4; ++j) {
                    const int kg = k0 + j * 16 + l15;
                    float pv = EXP2(fminf(s[j][r], 86.f));
                    if (needmask) pv = (kg > qg) ? 0.f : pv;
                    sP[wave][(quad * 4 + r) * SVS +
                             ((j * 16 + l15 + 16 * quad) & 63)] = (__bf16)pv;
                }
            }
        }

        // sP is wave-private: wave-local LDS drain (lgkm only, vmcnt alive)
        SCHED0;
        WAIT_LGKM0;
        SCHED0;

        if (active) {
#pragma unroll
            for (int kk = 0; kk < 2; ++kk) {
                bf16x8 pa, vb[4];
                pa = *(const bf16x8*)(
                    &sP[wave][l15 * SVS +
                              ((kk * 32 + quad * 8 + 16 * (l15 >> 2)) & 63)]);
#pragma unroll
                for (int j = 0; j < 4; ++j) {
                    const int gg = (2 * j + (l15 >> 3)) & 7;
                    vb[j] = *(const bf16x8*)(
                        sVT + (j * 16 + l15) * SVS +
                        ((kk * 32 + quad * 8 + 8 * ((5 * gg) & 7)) & 63));
                }
#pragma unroll
                for (int j = 0; j < 4; ++j)
                    o[j] = __builtin_amdgcn_mfma_f32_16x16x32_bf16(pa, vb[j], o[j], 0, 0, 0);
                o4 = __builtin_amdgcn_mfma_f32_16x16x32_bf16(pa, vone, o4, 0, 0, 0);
            }
        }
    }

    // epilogue: l = o4[r] (all cols equal); no shuffles needed
#pragma unroll
    for (int r = 0; r < 4; ++r) {
        const int qg  = wq0 + quad * 4 + r;
        const float inv = 1.f / o4[r];
#pragma unroll
        for (int j = 0; j < 4; ++j)
            base[(long)qg * rs + j * 16 + l15] = (__bf16)(o[j][r] * inv);
    }
}

// ---------------- diagnostic fallback (ws too small) ----------------
__global__ __launch_bounds__(256)
void fallback_k(float* __restrict__ out, long n, float wsmb) {
    long i = (long)blockIdx.x * blockDim.x + threadIdx.x;
    for (; i < n; i += (long)gridDim.x * blockDim.x) out[i] = 0.f;
    if (blockIdx.x == 0 && threadIdx.x == 0) out[0] = wsmb;
}

extern "C" void kernel_launch(void* const* d_in, const int* in_sizes, int n_in,
                              void* d_out, int out_size, void* d_ws, size_t ws_size,
                              hipStream_t stream) {
    const void* x     = d_in[0];   // [8192][1024] fp32
    const void* w_qkv = d_in[1];   // [1024][3072] fp32
    const void* w_out = d_in[2];   // [1024][1024] fp32
    const unsigned short* probe = (const unsigned short*)d_in[0];

    __bf16* qkv = (__bf16*)d_ws;                       // 48 MB
    __bf16* xb  = qkv + (size_t)8192 * 3072;           // +16 MB
    __bf16* wtq = xb  + (size_t)8192 * 1024;           // +6 MB
    __bf16* wto = wtq + (size_t)3072 * 1024;           // +2 MB  => 72 MB

    const size_t NEED_T1   = (size_t)72 * 1024 * 1024;
    const size_t NEED_FULL = (size_t)8192 * 3072 * 2;  // 48 MB
    const size_t NEED_B    = (size_t)2048 * 3072 * 2;  // 12 MB

    if (ws_size >= NEED_T1) {
        cvt_x<<<dim3(4096), 256, 0, stream>>>((const float*)x, xb, (long)8192 * 1024 / 8);
        tpose_cvt<<<dim3(96, 32), 256, 0, stream>>>((const float*)w_qkv, wtq, 1024, 3072);
        tpose_cvt<<<dim3(32, 32), 256, 0, stream>>>((const float*)w_out, wto, 1024, 1024);
        // gemm1: 64 bm x 24 bn = 1536 blocks, 3/CU co-resident stream
        gemm_p3<<<dim3(1536), 256, 0, stream>>>(xb, 1024, wtq, 1024, qkv, 3072, 0, 1024);
        // attn: 16 groups x 64 bh = 1024 blocks, lut-balanced
        attn_k<<<dim3(16 * 64), 512, 0, stream>>>(qkv, 6);
        // gemm2: R11 config (R12's 64x128 reshape was null-to-negative)
        gemm_p3<<<dim3(512), 256, 0, stream>>>(qkv, 3072, wto, 1024, d_out, 1024, 1, 1024);
    } else if (ws_size >= NEED_FULL) {
        gemm_bn<<<dim3(24, 64), 256, 0, stream>>>(
            x, 1024, 0, 1, w_qkv, 3072, 1, qkv, 3072, 0, 1024, probe);
        attn_k<<<dim3(16 * 64), 512, 0, stream>>>(qkv, 6);
        gemm_bn<<<dim3(8, 64), 256, 0, stream>>>(
            qkv, 3072, 0, 0, w_out, 1024, 1, d_out, 1024, 1, 1024, probe);
    } else if (ws_size >= NEED_B) {
        for (int b = 0; b < NB; ++b) {
            long xoff = (long)b * T_SEQ * DM;
            gemm_bn<<<dim3(24, 16), 256, 0, stream>>>(
                x, 1024, xoff, 1, w_qkv, 3072, 1, qkv, 3072, 0, 1024, probe);
            attn_k<<<dim3(16 * 16), 512, 0, stream>>>(qkv, 4);
            gemm_bn<<<dim3(8, 16), 256, 0, stream>>>(
                qkv, 3072, 0, 0, w_out, 1024, 1,
                (void*)((char*)d_out + (size_t)b * T_SEQ * DM * 4),
                1024, 1, 1024, probe);
        }
    } else {
        fallback_k<<<dim3(512), 256, 0, stream>>>(
            (float*)d_out, (long)8192 * 1024, (float)(ws_size >> 20));
    }
}